// Round 4
// baseline (335.146 us; speedup 1.0000x reference)
//
#include <hip/hip_runtime.h>
#include <hip/hip_bf16.h>

#define DM 2048
#define NH 4
#define DI 64
#define TQS 4096
#define TKS 4096
#define BB 2

typedef __attribute__((ext_vector_type(4))) float f32x4;
typedef __attribute__((ext_vector_type(8))) short bf16x8;

typedef __attribute__((address_space(1))) const void gvoid;
typedef __attribute__((address_space(3))) void lvoid;

__device__ __forceinline__ short f2bf(float f) {
  __hip_bfloat16 h = __float2bfloat16(f);
  return __builtin_bit_cast(short, h);
}

__device__ __forceinline__ bf16x8 cvt8(f32x4 a, f32x4 b) {
  bf16x8 r;
  r[0] = f2bf(a[0]); r[1] = f2bf(a[1]); r[2] = f2bf(a[2]); r[3] = f2bf(a[3]);
  r[4] = f2bf(b[0]); r[5] = f2bf(b[1]); r[6] = f2bf(b[2]); r[7] = f2bf(b[3]);
  return r;
}

// WqwT[320][2048]: rows 0-255 = Wq cols, 256-259 = Ww cols, 260-319 = 0.
__global__ __launch_bounds__(256) void transpose_qw(const float* __restrict__ Wq,
                                                    const float* __restrict__ Ww,
                                                    short* __restrict__ WT) {
  int idx = blockIdx.x * 256 + threadIdx.x;  // n*2048 + k
  int n = idx >> 11, k = idx & 2047;
  float v = 0.f;
  if (n < 256) v = Wq[(size_t)k * 256 + n];
  else if (n < 260) v = Ww[(size_t)k * 4 + (n - 256)];
  WT[idx] = f2bf(v);
}

// WkT[64][2048]
__global__ __launch_bounds__(256) void transpose_k(const float* __restrict__ Wk,
                                                   short* __restrict__ WT) {
  int idx = blockIdx.x * 256 + threadIdx.x;
  int n = idx >> 11, k = idx & 2047;
  WT[idx] = f2bf(Wk[(size_t)k * 64 + n]);
}

// proj v5: TLP fix. Rounds 2-3 ran 8 waves/CU (2 waves/SIMD) -> per-stage
// critical path (~1400 cyc) had no wave cover -> 5250 cyc/stage. Ring (ILP)
// was neutral; the machine wants TLP (m114/m97: implicit cross-block overlap
// at >=12 waves/CU is what works). Here: 512-thread/8-wave blocks on the SAME
// 32-row tile (waves = 2 row-groups x 4 col-groups; q-wave = 16 rows x 5
// tiles). Grid 512 -> 2 blocks/CU -> 16 waves/CU (4/SIMD), same per-block B
// traffic (no extra L2 load). __launch_bounds__(512,4) pins VGPR<=128: both
// blocks MUST be co-resident (VGPR>128 would quantize back to 8 waves/CU).
// Simple 2-phase drain (round-2 structure), 1 global_load_lds/thread/stage.
template <int NJ, bool QP>
__device__ __forceinline__ void proj_body(const float* __restrict__ X,
                                          const short* __restrict__ WT,
                                          short* __restrict__ O,
                                          float* __restrict__ wI, int blk,
                                          float* As /* [2][2048] LDS */) {
  const int tid = threadIdx.x;
  const int wave = tid >> 6, lane = tid & 63;
  const int wc = wave & 3, wr = wave >> 2;     // col-group, row-group
  const int l15 = lane & 15, quad = lane >> 4;
  const int m0 = blk * 32;
  const int ldo = QP ? 256 : 64;

  int jt[NJ];
#pragma unroll
  for (int jj = 0; jj < NJ; ++jj) jt[jj] = QP ? (jj < 4 ? jj * 4 + wc : 16 + wc) : wc;

  const short* wb[NJ];
#pragma unroll
  for (int jj = 0; jj < NJ; ++jj) wb[jj] = WT + (size_t)(jt[jj] * 16 + l15) * DM + quad * 8;

  // Stage: thread t fills LDS linear slot t*16 B (row t>>4, chunk t&15) from
  // pre-swizzled global chunk (t&15)^(row&15) (rule #21 both-sides swizzle).
  const int srow = tid >> 4;                    // 0..31
  const int schunk = (tid & 15) ^ (srow & 15);
  const float* s0 = X + (size_t)(m0 + srow) * DM + schunk * 4;
  const int d0 = tid * 16;
  char* lb = (char*)As;

  const f32x4 z = {0.f, 0.f, 0.f, 0.f};
  f32x4 acc[NJ];
#pragma unroll
  for (int jj = 0; jj < NJ; ++jj) acc[jj] = z;

  // prologue: stage t=0 into buf0
  __builtin_amdgcn_global_load_lds((gvoid*)s0, (lvoid*)(lb + d0), 16, 0, 0);
  __syncthreads();

  int cur = 0;
#pragma unroll 2
  for (int t = 0; t < 32; ++t) {
    // B for stage t (register loads, L2-hit).
    bf16x8 bbv[NJ][2];
#pragma unroll
    for (int jj = 0; jj < NJ; ++jj)
#pragma unroll
      for (int ks = 0; ks < 2; ++ks)
        bbv[jj][ks] = *(const bf16x8*)(wb[jj] + t * 64 + ks * 32);
    __builtin_amdgcn_sched_barrier(0);

    if (t < 31)  // issue next stage into the other buffer; waited at syncthreads
      __builtin_amdgcn_global_load_lds((gvoid*)(s0 + (t + 1) * 64),
                                       (lvoid*)(lb + (cur ^ 1) * 8192 + d0), 16, 0, 0);
    __builtin_amdgcn_sched_barrier(0);

    // A fragments from LDS buf[cur]: wave's rows wr*16 + l15; 16 chunks/row,
    // chunk index XOR'd with l15 (matches staged swizzle).
    const float* Ab = As + cur * 2048;
    bf16x8 abf[2];
    {
      const int rb = (wr * 16 + l15) * 64;
#pragma unroll
      for (int ks = 0; ks < 2; ++ks) {
        const int cg = ks * 8 + quad * 2;
        f32x4 a0 = *(const f32x4*)(Ab + rb + ((cg ^ l15) << 2));
        f32x4 a1 = *(const f32x4*)(Ab + rb + (((cg + 1) ^ l15) << 2));
        abf[ks] = cvt8(a0, a1);
      }
    }

#pragma unroll
    for (int jj = 0; jj < NJ; ++jj)
#pragma unroll
      for (int ks = 0; ks < 2; ++ks)
        acc[jj] = __builtin_amdgcn_mfma_f32_16x16x32_bf16(abf[ks], bbv[jj][ks],
                                                          acc[jj], 0, 0, 0);

    __syncthreads();  // drains vmcnt -> buf[cur^1] complete; LDS reuse safe
    cur ^= 1;
  }

  // C/D: row = quad*4 + r, col = l15; wave's rows at m0 + wr*16.
#pragma unroll
  for (int jj = 0; jj < NJ; ++jj) {
    if (QP && jt[jj] >= 16) {
      if (jt[jj] == 16 && l15 < 4) {  // Ww columns -> wI (f32)
#pragma unroll
        for (int r = 0; r < 4; ++r)
          wI[(size_t)(m0 + wr * 16 + quad * 4 + r) * NH + l15] = acc[jj][r];
      }
    } else {
#pragma unroll
      for (int r = 0; r < 4; ++r)
        O[(size_t)(m0 + wr * 16 + quad * 4 + r) * ldo + jt[jj] * 16 + l15] =
            f2bf(acc[jj][r]);
    }
  }
}

__global__ __launch_bounds__(512, 4) void proj_fused(const float* __restrict__ xq,
                                                     const float* __restrict__ xk,
                                                     const short* __restrict__ WqwT,
                                                     const short* __restrict__ WkT,
                                                     short* __restrict__ qb,
                                                     short* __restrict__ kb,
                                                     float* __restrict__ wIb) {
  __shared__ __align__(16) float As[2][2048];  // 16 KB: 2 x [32 rows][64 f32]
  if (blockIdx.x < 256)
    proj_body<5, true>(xq, WqwT, qb, wIb, blockIdx.x, &As[0][0]);
  else
    proj_body<1, false>(xk, WkT, kb, nullptr, blockIdx.x - 256, &As[0][0]);
}

// out[b][q][k] = sum_h wI[b,q,h] * relu(qb[b,q,h,:] . kb[b,k,:])
// 128x128 tile/block, 4 waves of 64x64. No LDS/barriers; af double-buffered over heads.
__global__ __launch_bounds__(256, 2) void score_kernel(const short* __restrict__ qb,
                                                       const short* __restrict__ kb,
                                                       const float* __restrict__ wI,
                                                       float* __restrict__ out) {
  const int b = blockIdx.z;
  const int qt = blockIdx.y;
  const int kt = blockIdx.x;
  const int tid = threadIdx.x;
  const int wave = tid >> 6, lane = tid & 63;
  const int wm = wave >> 1, wn = wave & 1;
  const int l15 = lane & 15, quad = lane >> 4;

  // Key fragments: B[k=quad*8+j][n=l15]; reused across all heads.
  bf16x8 bf[4][2];
  {
    const short* kbase =
        kb + (size_t)(b * TKS + kt * 128 + wn * 64 + l15) * DI + quad * 8;
#pragma unroll
    for (int j = 0; j < 4; ++j)
#pragma unroll
      for (int ks = 0; ks < 2; ++ks)
        bf[j][ks] = *(const bf16x8*)(kbase + j * 16 * DI + ks * 32);
  }

  const f32x4 z = {0.f, 0.f, 0.f, 0.f};
  f32x4 facc[4][4];
#pragma unroll
  for (int i = 0; i < 4; ++i)
#pragma unroll
    for (int j = 0; j < 4; ++j) facc[i][j] = z;

  const short* qbase =
      qb + (size_t)(b * TQS + qt * 128 + wm * 64 + l15) * (NH * DI) + quad * 8;
  const float* wbase = wI + (size_t)(b * TQS + qt * 128 + wm * 64 + quad * 4) * NH;

  bf16x8 af[2][4][2];
#pragma unroll
  for (int i = 0; i < 4; ++i)
#pragma unroll
    for (int ks = 0; ks < 2; ++ks)
      af[0][i][ks] = *(const bf16x8*)(qbase + i * 16 * (NH * DI) + ks * 32);

#pragma unroll
  for (int h = 0; h < NH; ++h) {
    if (h < NH - 1) {  // prefetch next head's A fragments (covered by MFMA+epilogue)
#pragma unroll
      for (int i = 0; i < 4; ++i)
#pragma unroll
        for (int ks = 0; ks < 2; ++ks)
          af[(h + 1) & 1][i][ks] =
              *(const bf16x8*)(qbase + (h + 1) * DI + i * 16 * (NH * DI) + ks * 32);
    }

    f32x4 acc[4][4];
#pragma unroll
    for (int i = 0; i < 4; ++i)
#pragma unroll
      for (int j = 0; j < 4; ++j) acc[i][j] = z;

#pragma unroll
    for (int ks = 0; ks < 2; ++ks)
#pragma unroll
      for (int i = 0; i < 4; ++i)
#pragma unroll
        for (int j = 0; j < 4; ++j)
          acc[i][j] = __builtin_amdgcn_mfma_f32_16x16x32_bf16(
              af[h & 1][i][ks], bf[j][ks], acc[i][j], 0, 0, 0);

#pragma unroll
    for (int i = 0; i < 4; ++i) {
      float wv[4];
#pragma unroll
      for (int r = 0; r < 4; ++r) wv[r] = wbase[(i * 16 + r) * NH + h];
#pragma unroll
      for (int j = 0; j < 4; ++j)
#pragma unroll
        for (int r = 0; r < 4; ++r)
          facc[i][j][r] += wv[r] * fmaxf(acc[i][j][r], 0.f);
    }
  }

  float* obase = out + (size_t)b * TQS * TKS +
                 (size_t)(qt * 128 + wm * 64 + quad * 4) * TKS + kt * 128 + wn * 64 + l15;
#pragma unroll
  for (int i = 0; i < 4; ++i)
#pragma unroll
    for (int r = 0; r < 4; ++r)
#pragma unroll
      for (int j = 0; j < 4; ++j)
        __builtin_nontemporal_store(facc[i][j][r],
                                    &obase[(size_t)(i * 16 + r) * TKS + j * 16]);
}

extern "C" void kernel_launch(void* const* d_in, const int* in_sizes, int n_in,
                              void* d_out, int out_size, void* d_ws, size_t ws_size,
                              hipStream_t stream) {
  const float* x_q = (const float*)d_in[0];  // [2,4096,2048]
  const float* x_k = (const float*)d_in[1];  // [2,4096,2048]
  const float* Wq  = (const float*)d_in[2];  // [2048,256]
  const float* Ww  = (const float*)d_in[3];  // [2048,4]
  const float* Wk  = (const float*)d_in[4];  // [2048,64]
  float* out = (float*)d_out;                // [2,4096,4096]

  char* ws = (char*)d_ws;
  short* qbuf = (short*)(ws);                              // 8192*256 bf16 = 4 MB
  short* kbuf = (short*)(ws + (4u << 20));                 // 8192*64  bf16 = 1 MB
  float* wIb  = (float*)(ws + (5u << 20));                 // 8192*4 f32 = 128 KB
  short* WqwT = (short*)(ws + (5u << 20) + (128u << 10));  // 320*2048 bf16 = 1.25 MB
  short* WkT  = (short*)(ws + (7u << 20));                 // 64*2048 bf16 = 256 KB

  transpose_qw<<<(320 * 2048) / 256, 256, 0, stream>>>(Wq, Ww, WqwT);
  transpose_k<<<(64 * 2048) / 256, 256, 0, stream>>>(Wk, WkT);

  // Fused projections: blocks 0-255 -> q (+w), 256-511 -> k. x read exactly once.
  proj_fused<<<512, 512, 0, stream>>>(x_q, x_k, WqwT, WkT, qbuf, kbuf, wIb);

  score_kernel<<<dim3(TKS / 128, TQS / 128, BB), 256, 0, stream>>>(qbuf, kbuf, wIb, out);
}

// Round 5
// 311.950 us; speedup vs baseline: 1.0744x; 1.0744x over previous
//
#include <hip/hip_runtime.h>
#include <hip/hip_bf16.h>

#define DM 2048
#define NH 4
#define DI 64
#define TQS 4096
#define TKS 4096
#define BB 2

typedef __attribute__((ext_vector_type(4))) float f32x4;
typedef __attribute__((ext_vector_type(8))) short bf16x8;

typedef __attribute__((address_space(1))) const void gvoid;
typedef __attribute__((address_space(3))) void lvoid;

__device__ __forceinline__ short f2bf(float f) {
  __hip_bfloat16 h = __float2bfloat16(f);
  return __builtin_bit_cast(short, h);
}

__device__ __forceinline__ bf16x8 cvt8(f32x4 a, f32x4 b) {
  bf16x8 r;
  r[0] = f2bf(a[0]); r[1] = f2bf(a[1]); r[2] = f2bf(a[2]); r[3] = f2bf(a[3]);
  r[4] = f2bf(b[0]); r[5] = f2bf(b[1]); r[6] = f2bf(b[2]); r[7] = f2bf(b[3]);
  return r;
}

// WqwT[320][2048]: rows 0-255 = Wq cols, 256-259 = Ww cols, 260-319 = 0.
__global__ __launch_bounds__(256) void transpose_qw(const float* __restrict__ Wq,
                                                    const float* __restrict__ Ww,
                                                    short* __restrict__ WT) {
  int idx = blockIdx.x * 256 + threadIdx.x;  // n*2048 + k
  int n = idx >> 11, k = idx & 2047;
  float v = 0.f;
  if (n < 256) v = Wq[(size_t)k * 256 + n];
  else if (n < 260) v = Ww[(size_t)k * 4 + (n - 256)];
  WT[idx] = f2bf(v);
}

// WkT[64][2048]
__global__ __launch_bounds__(256) void transpose_k(const float* __restrict__ Wk,
                                                   short* __restrict__ WT) {
  int idx = blockIdx.x * 256 + threadIdx.x;
  int n = idx >> 11, k = idx & 2047;
  WT[idx] = f2bf(Wk[(size_t)k * 64 + n]);
}

// proj v6: amortization fix. Model fitting rounds 2-4: BW/CU = stage_bytes /
// period, period pinned by per-stage fixed costs (B L2 round-trip serialized
// by the in-order vmcnt queue + stage HBM round-trip + barrier). Round 2:
// 8 KB/5250cyc = 3 B/cyc/CU. Neither ring-ILP (r3) nor 2x TLP (r4) moved it.
// Fix: BK=256 -> 32 KB/stage (4x bytes per fixed cost), 8 stages total.
// B: 2-ahead register double-buffer issued BEFORE the A-stage so queue order
// is B0,B1 < stage(t+1) < B2,B3: kk0/kk1 B-waits drain nothing; the one
// exposed stage-drain lands at kk2 (~halfway, latency mostly elapsed).
// 256 thr / 4 waves / 32-row tile (round-2 shape), 2 blocks/CU, LDS 128 KB/CU.
template <int NJ, bool QP>
__device__ __forceinline__ void proj_body(const float* __restrict__ X,
                                          const short* __restrict__ WT,
                                          short* __restrict__ O,
                                          float* __restrict__ wI, int blk,
                                          float* As /* [2][8192] LDS */) {
  const int tid = threadIdx.x;
  const int wave = tid >> 6, lane = tid & 63;
  const int l15 = lane & 15, quad = lane >> 4;
  const int m0 = blk * 32;
  const int ldo = QP ? 256 : 64;

  int jt[NJ];
#pragma unroll
  for (int jj = 0; jj < NJ; ++jj) jt[jj] = QP ? (jj < 4 ? jj * 4 + wave : 16 + wave) : wave;

  const short* wb[NJ];
#pragma unroll
  for (int jj = 0; jj < NJ; ++jj) wb[jj] = WT + (size_t)(jt[jj] * 16 + l15) * DM + quad * 8;

  char* lb = (char*)As;

  // Stage: 32 rows x 256 floats = 32 KB. Thread t, issue j (0..7): writes LDS
  // slot j*256+t (16 B slots) = row j*4+wave, chunk lane -> dest is wave-
  // uniform base + lane*16 (HW requirement). Source chunk pre-swizzled
  // lane ^ (row&15) (rule #21; read side applies same XOR).
  auto stage = [&](int tn, int buf) {
#pragma unroll
    for (int j = 0; j < 8; ++j) {
      const int row = j * 4 + wave;  // wave-uniform
      const float* src = X + (size_t)(m0 + row) * DM + tn * 256 + ((lane ^ (row & 15)) << 2);
      char* dst = lb + buf * 32768 + (j * 256 + tid) * 16;
      __builtin_amdgcn_global_load_lds((gvoid*)src, (lvoid*)dst, 16, 0, 0);
    }
  };

  bf16x8 bbv[2][NJ][2];
  auto loadB = [&](int k64, int p) {
#pragma unroll
    for (int jj = 0; jj < NJ; ++jj)
#pragma unroll
      for (int ks = 0; ks < 2; ++ks)
        bbv[p][jj][ks] = *(const bf16x8*)(wb[jj] + k64 * 64 + ks * 32);
  };

  const f32x4 z = {0.f, 0.f, 0.f, 0.f};
  f32x4 acc[NJ][2];
#pragma unroll
  for (int jj = 0; jj < NJ; ++jj)
#pragma unroll
    for (int i = 0; i < 2; ++i) acc[jj][i] = z;

  auto computeKK = [&](int buf, int kk, int p) {
    const float* Ab = As + buf * 8192;
    bf16x8 abf[2][2];
#pragma unroll
    for (int i = 0; i < 2; ++i) {
      const int rb = (i * 16 + l15) * 256;
#pragma unroll
      for (int ks = 0; ks < 2; ++ks) {
        const int cg = kk * 16 + ks * 8 + quad * 2;
        f32x4 a0 = *(const f32x4*)(Ab + rb + ((cg ^ l15) << 2));
        f32x4 a1 = *(const f32x4*)(Ab + rb + (((cg + 1) ^ l15) << 2));
        abf[i][ks] = cvt8(a0, a1);
      }
    }
#pragma unroll
    for (int jj = 0; jj < NJ; ++jj)
#pragma unroll
      for (int i = 0; i < 2; ++i)
#pragma unroll
        for (int ks = 0; ks < 2; ++ks)
          acc[jj][i] = __builtin_amdgcn_mfma_f32_16x16x32_bf16(abf[i][ks], bbv[p][jj][ks],
                                                               acc[jj][i], 0, 0, 0);
  };

  // prologue
  stage(0, 0);
  __syncthreads();

#pragma unroll 2
  for (int t = 0; t < 8; ++t) {
    const int buf = t & 1;
    loadB(t * 4 + 0, 0);           // queue: B0,B1 first ...
    loadB(t * 4 + 1, 1);
    __builtin_amdgcn_sched_barrier(0);
    if (t < 7) stage(t + 1, buf ^ 1);  // ... then next A-stage ...
    __builtin_amdgcn_sched_barrier(0);
    computeKK(buf, 0, 0);          // wait B0: drains only B0
    loadB(t * 4 + 2, 0);           // ... then B2,B3 (issued after consume)
    __builtin_amdgcn_sched_barrier(0);
    computeKK(buf, 1, 1);          // wait B1: still older than stage -> free
    loadB(t * 4 + 3, 1);
    __builtin_amdgcn_sched_barrier(0);
    computeKK(buf, 2, 0);          // wait B2: the one exposed stage-drain
    __builtin_amdgcn_sched_barrier(0);
    computeKK(buf, 3, 1);
    __builtin_amdgcn_sched_barrier(0);
    __syncthreads();               // stage already drained at kk2 -> cheap
  }

  // C/D: row = quad*4 + r, col = l15
#pragma unroll
  for (int jj = 0; jj < NJ; ++jj) {
    if (QP && jt[jj] >= 16) {
      if (jt[jj] == 16 && l15 < 4) {  // Ww columns -> wI (f32)
#pragma unroll
        for (int i = 0; i < 2; ++i)
#pragma unroll
          for (int r = 0; r < 4; ++r)
            wI[(size_t)(m0 + i * 16 + quad * 4 + r) * NH + l15] = acc[jj][i][r];
      }
    } else {
#pragma unroll
      for (int i = 0; i < 2; ++i)
#pragma unroll
        for (int r = 0; r < 4; ++r)
          O[(size_t)(m0 + i * 16 + quad * 4 + r) * ldo + jt[jj] * 16 + l15] =
              f2bf(acc[jj][i][r]);
    }
  }
}

__global__ __launch_bounds__(256, 2) void proj_fused(const float* __restrict__ xq,
                                                     const float* __restrict__ xk,
                                                     const short* __restrict__ WqwT,
                                                     const short* __restrict__ WkT,
                                                     short* __restrict__ qb,
                                                     short* __restrict__ kb,
                                                     float* __restrict__ wIb) {
  __shared__ __align__(16) float As[2][8192];  // 64 KB: 2 x [32 rows][256 f32]
  if (blockIdx.x < 256)
    proj_body<5, true>(xq, WqwT, qb, wIb, blockIdx.x, &As[0][0]);
  else
    proj_body<1, false>(xk, WkT, kb, nullptr, blockIdx.x - 256, &As[0][0]);
}

// out[b][q][k] = sum_h wI[b,q,h] * relu(qb[b,q,h,:] . kb[b,k,:])
// 128x128 tile/block, 4 waves of 64x64. No LDS/barriers; af double-buffered over heads.
__global__ __launch_bounds__(256, 2) void score_kernel(const short* __restrict__ qb,
                                                       const short* __restrict__ kb,
                                                       const float* __restrict__ wI,
                                                       float* __restrict__ out) {
  const int b = blockIdx.z;
  const int qt = blockIdx.y;
  const int kt = blockIdx.x;
  const int tid = threadIdx.x;
  const int wave = tid >> 6, lane = tid & 63;
  const int wm = wave >> 1, wn = wave & 1;
  const int l15 = lane & 15, quad = lane >> 4;

  // Key fragments: B[k=quad*8+j][n=l15]; reused across all heads.
  bf16x8 bf[4][2];
  {
    const short* kbase =
        kb + (size_t)(b * TKS + kt * 128 + wn * 64 + l15) * DI + quad * 8;
#pragma unroll
    for (int j = 0; j < 4; ++j)
#pragma unroll
      for (int ks = 0; ks < 2; ++ks)
        bf[j][ks] = *(const bf16x8*)(kbase + j * 16 * DI + ks * 32);
  }

  const f32x4 z = {0.f, 0.f, 0.f, 0.f};
  f32x4 facc[4][4];
#pragma unroll
  for (int i = 0; i < 4; ++i)
#pragma unroll
    for (int j = 0; j < 4; ++j) facc[i][j] = z;

  const short* qbase =
      qb + (size_t)(b * TQS + qt * 128 + wm * 64 + l15) * (NH * DI) + quad * 8;
  const float* wbase = wI + (size_t)(b * TQS + qt * 128 + wm * 64 + quad * 4) * NH;

  bf16x8 af[2][4][2];
#pragma unroll
  for (int i = 0; i < 4; ++i)
#pragma unroll
    for (int ks = 0; ks < 2; ++ks)
      af[0][i][ks] = *(const bf16x8*)(qbase + i * 16 * (NH * DI) + ks * 32);

#pragma unroll
  for (int h = 0; h < NH; ++h) {
    if (h < NH - 1) {  // prefetch next head's A fragments (covered by MFMA+epilogue)
#pragma unroll
      for (int i = 0; i < 4; ++i)
#pragma unroll
        for (int ks = 0; ks < 2; ++ks)
          af[(h + 1) & 1][i][ks] =
              *(const bf16x8*)(qbase + (h + 1) * DI + i * 16 * (NH * DI) + ks * 32);
    }

    f32x4 acc[4][4];
#pragma unroll
    for (int i = 0; i < 4; ++i)
#pragma unroll
      for (int j = 0; j < 4; ++j) acc[i][j] = z;

#pragma unroll
    for (int ks = 0; ks < 2; ++ks)
#pragma unroll
      for (int i = 0; i < 4; ++i)
#pragma unroll
        for (int j = 0; j < 4; ++j)
          acc[i][j] = __builtin_amdgcn_mfma_f32_16x16x32_bf16(
              af[h & 1][i][ks], bf[j][ks], acc[i][j], 0, 0, 0);

#pragma unroll
    for (int i = 0; i < 4; ++i) {
      float wv[4];
#pragma unroll
      for (int r = 0; r < 4; ++r) wv[r] = wbase[(i * 16 + r) * NH + h];
#pragma unroll
      for (int j = 0; j < 4; ++j)
#pragma unroll
        for (int r = 0; r < 4; ++r)
          facc[i][j][r] += wv[r] * fmaxf(acc[i][j][r], 0.f);
    }
  }

  float* obase = out + (size_t)b * TQS * TKS +
                 (size_t)(qt * 128 + wm * 64 + quad * 4) * TKS + kt * 128 + wn * 64 + l15;
#pragma unroll
  for (int i = 0; i < 4; ++i)
#pragma unroll
    for (int r = 0; r < 4; ++r)
#pragma unroll
      for (int j = 0; j < 4; ++j)
        __builtin_nontemporal_store(facc[i][j][r],
                                    &obase[(size_t)(i * 16 + r) * TKS + j * 16]);
}

extern "C" void kernel_launch(void* const* d_in, const int* in_sizes, int n_in,
                              void* d_out, int out_size, void* d_ws, size_t ws_size,
                              hipStream_t stream) {
  const float* x_q = (const float*)d_in[0];  // [2,4096,2048]
  const float* x_k = (const float*)d_in[1];  // [2,4096,2048]
  const float* Wq  = (const float*)d_in[2];  // [2048,256]
  const float* Ww  = (const float*)d_in[3];  // [2048,4]
  const float* Wk  = (const float*)d_in[4];  // [2048,64]
  float* out = (float*)d_out;                // [2,4096,4096]

  char* ws = (char*)d_ws;
  short* qbuf = (short*)(ws);                              // 8192*256 bf16 = 4 MB
  short* kbuf = (short*)(ws + (4u << 20));                 // 8192*64  bf16 = 1 MB
  float* wIb  = (float*)(ws + (5u << 20));                 // 8192*4 f32 = 128 KB
  short* WqwT = (short*)(ws + (5u << 20) + (128u << 10));  // 320*2048 bf16 = 1.25 MB
  short* WkT  = (short*)(ws + (7u << 20));                 // 64*2048 bf16 = 256 KB

  transpose_qw<<<(320 * 2048) / 256, 256, 0, stream>>>(Wq, Ww, WqwT);
  transpose_k<<<(64 * 2048) / 256, 256, 0, stream>>>(Wk, WkT);

  // Fused projections: blocks 0-255 -> q (+w), 256-511 -> k. x read exactly once.
  proj_fused<<<512, 256, 0, stream>>>(x_q, x_k, WqwT, WkT, qbuf, kbuf, wIb);

  score_kernel<<<dim3(TKS / 128, TQS / 128, BB), 256, 0, stream>>>(qbuf, kbuf, wIb, out);
}

// Round 6
// 298.013 us; speedup vs baseline: 1.1246x; 1.0468x over previous
//
#include <hip/hip_runtime.h>
#include <hip/hip_bf16.h>

#define DM 2048
#define NH 4
#define DI 64
#define TQS 4096
#define TKS 4096
#define BB 2

typedef __attribute__((ext_vector_type(4))) float f32x4;
typedef __attribute__((ext_vector_type(8))) short bf16x8;

typedef __attribute__((address_space(1))) const void gvoid;
typedef __attribute__((address_space(3))) void lvoid;

__device__ __forceinline__ short f2bf(float f) {
  __hip_bfloat16 h = __float2bfloat16(f);
  return __builtin_bit_cast(short, h);
}

__device__ __forceinline__ bf16x8 cvt8(f32x4 a, f32x4 b) {
  bf16x8 r;
  r[0] = f2bf(a[0]); r[1] = f2bf(a[1]); r[2] = f2bf(a[2]); r[3] = f2bf(a[3]);
  r[4] = f2bf(b[0]); r[5] = f2bf(b[1]); r[6] = f2bf(b[2]); r[7] = f2bf(b[3]);
  return r;
}

// Round-5 lesson: proj was cache-line-REQUEST-bound (1.06 lines/cyc/CU fit
// across r2-r5). Old WT layout made every B-load 64 lines/inst (16-B reads at
// 4-KB row stride). Fix: pack W into MFMA-fragment order so each B-load inst
// reads 64 lanes x 16 B CONTIGUOUS (16 lines/inst, the minimum).
// Pq[jt][k64][ks][lane][8]: element = W[k = k64*64+ks*32+(lane>>4)*8+j]
//                                      [n = jt*16+(lane&15)]
// jt 0..15 = Wq cols; jt=16 cols 0-3 = Ww; rest zero. 1.25 MB.
__global__ __launch_bounds__(256) void pack_qw(const float* __restrict__ Wq,
                                               const float* __restrict__ Ww,
                                               short* __restrict__ P) {
  int idx = blockIdx.x * 256 + threadIdx.x;  // short idx, total 20*32*2*64*8
  int j = idx & 7;
  int lane = (idx >> 3) & 63;
  int ks = (idx >> 9) & 1;
  int k64 = (idx >> 10) & 31;
  int jt = idx >> 15;
  int n = jt * 16 + (lane & 15);
  int k = k64 * 64 + ks * 32 + (lane >> 4) * 8 + j;
  float v = 0.f;
  if (n < 256) v = Wq[(size_t)k * 256 + n];
  else if (n < 260) v = Ww[(size_t)k * 4 + (n - 256)];
  P[idx] = f2bf(v);
}

// Pk[jt][k64][ks][lane][8], jt 0..3 over Wk's 64 cols. 256 KB.
__global__ __launch_bounds__(256) void pack_k(const float* __restrict__ Wk,
                                              short* __restrict__ P) {
  int idx = blockIdx.x * 256 + threadIdx.x;  // total 4*32*2*64*8
  int j = idx & 7;
  int lane = (idx >> 3) & 63;
  int ks = (idx >> 9) & 1;
  int k64 = (idx >> 10) & 31;
  int jt = idx >> 15;
  int n = jt * 16 + (lane & 15);
  int k = k64 * 64 + ks * 32 + (lane >> 4) * 8 + j;
  P[idx] = f2bf(Wk[(size_t)k * 64 + n]);
}

// proj v7: round-2 structure (best measured: BK=64, 2-deep LDS, 256 thr,
// 2 blocks/CU) with fragment-packed B (coalesced 1-KB loads, 16 lines/inst).
// A-stage: rule-#21 both-sides swizzle, 1 global_load_lds dwordx4 x2/thread.
template <int NJ, bool QP>
__device__ __forceinline__ void proj_body(const float* __restrict__ X,
                                          const short* __restrict__ P,
                                          short* __restrict__ O,
                                          float* __restrict__ wI, int blk,
                                          float* As /* [2][2048] LDS */) {
  const int tid = threadIdx.x;
  const int wave = tid >> 6, lane = tid & 63;
  const int l15 = lane & 15, quad = lane >> 4;
  const int m0 = blk * 32;
  const int ldo = QP ? 256 : 64;

  int jt[NJ];
#pragma unroll
  for (int jj = 0; jj < NJ; ++jj) jt[jj] = QP ? (jj < 4 ? jj * 4 + wave : 16 + wave) : wave;

  // Packed-B bases: per (jt): 32 k64 * 2 ks * 64 lanes * 8 shorts = 32768.
  const short* wb[NJ];
#pragma unroll
  for (int jj = 0; jj < NJ; ++jj) wb[jj] = P + (size_t)jt[jj] * 32768 + lane * 8;

  // Stage: thread t fills LDS slots {t*16, 4096+t*16} (rows srow, srow+16)
  // from pre-swizzled global chunk (t&15)^srow (read side applies same XOR).
  const int srow = tid >> 4;
  const int schunk = (tid & 15) ^ srow;
  const float* s0 = X + (size_t)(m0 + srow) * DM + schunk * 4;
  const float* s1 = X + (size_t)(m0 + 16 + srow) * DM + schunk * 4;
  const int d0 = tid * 16, d1 = 4096 + tid * 16;
  char* lb = (char*)As;

  const f32x4 z = {0.f, 0.f, 0.f, 0.f};
  f32x4 acc[NJ][2];
#pragma unroll
  for (int jj = 0; jj < NJ; ++jj)
#pragma unroll
    for (int i = 0; i < 2; ++i) acc[jj][i] = z;

  // prologue: stage t=0 into buf0
  __builtin_amdgcn_global_load_lds((gvoid*)s0, (lvoid*)(lb + d0), 16, 0, 0);
  __builtin_amdgcn_global_load_lds((gvoid*)s1, (lvoid*)(lb + d1), 16, 0, 0);
  __syncthreads();

  int cur = 0;
#pragma unroll 2
  for (int t = 0; t < 32; ++t) {
    // B for step t: NJ*2 coalesced 1-KB loads (packed layout).
    bf16x8 bbv[NJ][2];
#pragma unroll
    for (int jj = 0; jj < NJ; ++jj)
#pragma unroll
      for (int ks = 0; ks < 2; ++ks)
        bbv[jj][ks] = *(const bf16x8*)(wb[jj] + t * 1024 + ks * 512);
    __builtin_amdgcn_sched_barrier(0);  // B older than stage in vmcnt queue

    if (t < 31) {  // issue next stage into the other buffer
      const float* g0 = s0 + (t + 1) * 64;
      const float* g1 = s1 + (t + 1) * 64;
      char* l = lb + (cur ^ 1) * 8192;
      __builtin_amdgcn_global_load_lds((gvoid*)g0, (lvoid*)(l + d0), 16, 0, 0);
      __builtin_amdgcn_global_load_lds((gvoid*)g1, (lvoid*)(l + d1), 16, 0, 0);
    }
    __builtin_amdgcn_sched_barrier(0);  // stage issued before compute's waits

    // A fragments from LDS buf[cur]: row i*16+l15, chunks XOR'd with l15.
    const float* Ab = As + cur * 2048;
    bf16x8 abf[2][2];
#pragma unroll
    for (int i = 0; i < 2; ++i)
#pragma unroll
      for (int ks = 0; ks < 2; ++ks) {
        const int rb = (i * 16 + l15) * 64;
        const int cg = ks * 8 + quad * 2;
        f32x4 a0 = *(const f32x4*)(Ab + rb + ((cg ^ l15) << 2));
        f32x4 a1 = *(const f32x4*)(Ab + rb + (((cg + 1) ^ l15) << 2));
        abf[i][ks] = cvt8(a0, a1);
      }

#pragma unroll
    for (int jj = 0; jj < NJ; ++jj)
#pragma unroll
      for (int i = 0; i < 2; ++i)
#pragma unroll
        for (int ks = 0; ks < 2; ++ks)
          acc[jj][i] = __builtin_amdgcn_mfma_f32_16x16x32_bf16(abf[i][ks], bbv[jj][ks],
                                                               acc[jj][i], 0, 0, 0);

    __syncthreads();  // drains vmcnt -> buf[cur^1] staged; LDS reuse safe
    cur ^= 1;
  }

  // C/D: row = quad*4 + r, col = l15
#pragma unroll
  for (int jj = 0; jj < NJ; ++jj) {
    if (QP && jt[jj] >= 16) {
      if (jt[jj] == 16 && l15 < 4) {  // Ww columns -> wI (f32)
#pragma unroll
        for (int i = 0; i < 2; ++i)
#pragma unroll
          for (int r = 0; r < 4; ++r)
            wI[(size_t)(m0 + i * 16 + quad * 4 + r) * NH + l15] = acc[jj][i][r];
      }
    } else {
#pragma unroll
      for (int i = 0; i < 2; ++i)
#pragma unroll
        for (int r = 0; r < 4; ++r)
          O[(size_t)(m0 + i * 16 + quad * 4 + r) * ldo + jt[jj] * 16 + l15] =
              f2bf(acc[jj][i][r]);
    }
  }
}

__global__ __launch_bounds__(256, 2) void proj_fused(const float* __restrict__ xq,
                                                     const float* __restrict__ xk,
                                                     const short* __restrict__ Pq,
                                                     const short* __restrict__ Pk,
                                                     short* __restrict__ qb,
                                                     short* __restrict__ kb,
                                                     float* __restrict__ wIb) {
  __shared__ __align__(16) float As[2][2048];  // 16 KB: 2 x [32 rows][64 f32]
  if (blockIdx.x < 256)
    proj_body<5, true>(xq, Pq, qb, wIb, blockIdx.x, &As[0][0]);
  else
    proj_body<1, false>(xk, Pk, kb, nullptr, blockIdx.x - 256, &As[0][0]);
}

// out[b][q][k] = sum_h wI[b,q,h] * relu(qb[b,q,h,:] . kb[b,k,:])
// 128x128 tile/block, 4 waves of 64x64. No LDS/barriers; af double-buffered over heads.
__global__ __launch_bounds__(256, 2) void score_kernel(const short* __restrict__ qb,
                                                       const short* __restrict__ kb,
                                                       const float* __restrict__ wI,
                                                       float* __restrict__ out) {
  const int b = blockIdx.z;
  const int qt = blockIdx.y;
  const int kt = blockIdx.x;
  const int tid = threadIdx.x;
  const int wave = tid >> 6, lane = tid & 63;
  const int wm = wave >> 1, wn = wave & 1;
  const int l15 = lane & 15, quad = lane >> 4;

  // Key fragments: B[k=quad*8+j][n=l15]; reused across all heads.
  bf16x8 bf[4][2];
  {
    const short* kbase =
        kb + (size_t)(b * TKS + kt * 128 + wn * 64 + l15) * DI + quad * 8;
#pragma unroll
    for (int j = 0; j < 4; ++j)
#pragma unroll
      for (int ks = 0; ks < 2; ++ks)
        bf[j][ks] = *(const bf16x8*)(kbase + j * 16 * DI + ks * 32);
  }

  const f32x4 z = {0.f, 0.f, 0.f, 0.f};
  f32x4 facc[4][4];
#pragma unroll
  for (int i = 0; i < 4; ++i)
#pragma unroll
    for (int j = 0; j < 4; ++j) facc[i][j] = z;

  const short* qbase =
      qb + (size_t)(b * TQS + qt * 128 + wm * 64 + l15) * (NH * DI) + quad * 8;
  const float* wbase = wI + (size_t)(b * TQS + qt * 128 + wm * 64 + quad * 4) * NH;

  bf16x8 af[2][4][2];
#pragma unroll
  for (int i = 0; i < 4; ++i)
#pragma unroll
    for (int ks = 0; ks < 2; ++ks)
      af[0][i][ks] = *(const bf16x8*)(qbase + i * 16 * (NH * DI) + ks * 32);

#pragma unroll
  for (int h = 0; h < NH; ++h) {
    if (h < NH - 1) {  // prefetch next head's A fragments (covered by MFMA+epilogue)
#pragma unroll
      for (int i = 0; i < 4; ++i)
#pragma unroll
        for (int ks = 0; ks < 2; ++ks)
          af[(h + 1) & 1][i][ks] =
              *(const bf16x8*)(qbase + (h + 1) * DI + i * 16 * (NH * DI) + ks * 32);
    }

    f32x4 acc[4][4];
#pragma unroll
    for (int i = 0; i < 4; ++i)
#pragma unroll
      for (int j = 0; j < 4; ++j) acc[i][j] = z;

#pragma unroll
    for (int ks = 0; ks < 2; ++ks)
#pragma unroll
      for (int i = 0; i < 4; ++i)
#pragma unroll
        for (int j = 0; j < 4; ++j)
          acc[i][j] = __builtin_amdgcn_mfma_f32_16x16x32_bf16(
              af[h & 1][i][ks], bf[j][ks], acc[i][j], 0, 0, 0);

#pragma unroll
    for (int i = 0; i < 4; ++i) {
      float wv[4];
#pragma unroll
      for (int r = 0; r < 4; ++r) wv[r] = wbase[(i * 16 + r) * NH + h];
#pragma unroll
      for (int j = 0; j < 4; ++j)
#pragma unroll
        for (int r = 0; r < 4; ++r)
          facc[i][j][r] += wv[r] * fmaxf(acc[i][j][r], 0.f);
    }
  }

  float* obase = out + (size_t)b * TQS * TKS +
                 (size_t)(qt * 128 + wm * 64 + quad * 4) * TKS + kt * 128 + wn * 64 + l15;
#pragma unroll
  for (int i = 0; i < 4; ++i)
#pragma unroll
    for (int r = 0; r < 4; ++r)
#pragma unroll
      for (int j = 0; j < 4; ++j)
        __builtin_nontemporal_store(facc[i][j][r],
                                    &obase[(size_t)(i * 16 + r) * TKS + j * 16]);
}

extern "C" void kernel_launch(void* const* d_in, const int* in_sizes, int n_in,
                              void* d_out, int out_size, void* d_ws, size_t ws_size,
                              hipStream_t stream) {
  const float* x_q = (const float*)d_in[0];  // [2,4096,2048]
  const float* x_k = (const float*)d_in[1];  // [2,4096,2048]
  const float* Wq  = (const float*)d_in[2];  // [2048,256]
  const float* Ww  = (const float*)d_in[3];  // [2048,4]
  const float* Wk  = (const float*)d_in[4];  // [2048,64]
  float* out = (float*)d_out;                // [2,4096,4096]

  char* ws = (char*)d_ws;
  short* qbuf = (short*)(ws);                              // 8192*256 bf16 = 4 MB
  short* kbuf = (short*)(ws + (4u << 20));                 // 8192*64  bf16 = 1 MB
  float* wIb  = (float*)(ws + (5u << 20));                 // 8192*4 f32 = 128 KB
  short* Pq   = (short*)(ws + (5u << 20) + (128u << 10));  // 20*32768 bf16 = 1.25 MB
  short* Pk   = (short*)(ws + (7u << 20));                 // 4*32768 bf16 = 256 KB

  pack_qw<<<(20 * 32768) / 256, 256, 0, stream>>>(Wq, Ww, Pq);
  pack_k<<<(4 * 32768) / 256, 256, 0, stream>>>(Wk, Pk);

  // Fused projections: blocks 0-255 -> q (+w), 256-511 -> k. x read exactly once.
  proj_fused<<<512, 256, 0, stream>>>(x_q, x_k, Pq, Pk, qbuf, kbuf, wIb);

  score_kernel<<<dim3(TKS / 128, TQS / 128, BB), 256, 0, stream>>>(qbuf, kbuf, wIb, out);
}

// Round 7
// 292.095 us; speedup vs baseline: 1.1474x; 1.0203x over previous
//
#include <hip/hip_runtime.h>
#include <hip/hip_bf16.h>

#define DM 2048
#define NH 4
#define DI 64
#define TQS 4096
#define TKS 4096
#define BB 2

typedef __attribute__((ext_vector_type(4))) float f32x4;
typedef __attribute__((ext_vector_type(8))) short bf16x8;

typedef __attribute__((address_space(1))) const void gvoid;
typedef __attribute__((address_space(3))) void lvoid;

__device__ __forceinline__ short f2bf(float f) {
  __hip_bfloat16 h = __float2bfloat16(f);
  return __builtin_bit_cast(short, h);
}

__device__ __forceinline__ bf16x8 cvt8(f32x4 a, f32x4 b) {
  bf16x8 r;
  r[0] = f2bf(a[0]); r[1] = f2bf(a[1]); r[2] = f2bf(a[2]); r[3] = f2bf(a[3]);
  r[4] = f2bf(b[0]); r[5] = f2bf(b[1]); r[6] = f2bf(b[2]); r[7] = f2bf(b[3]);
  return r;
}

// Packed-B layout (round-6 win, kept): Pq[jt][k64][ks][lane][8] — each B-load
// instruction reads 64 lanes x 16 B CONTIGUOUS (16 lines/inst, minimum).
__global__ __launch_bounds__(256) void pack_qw(const float* __restrict__ Wq,
                                               const float* __restrict__ Ww,
                                               short* __restrict__ P) {
  int idx = blockIdx.x * 256 + threadIdx.x;  // total 20*32*2*64*8
  int j = idx & 7;
  int lane = (idx >> 3) & 63;
  int ks = (idx >> 9) & 1;
  int k64 = (idx >> 10) & 31;
  int jt = idx >> 15;
  int n = jt * 16 + (lane & 15);
  int k = k64 * 64 + ks * 32 + (lane >> 4) * 8 + j;
  float v = 0.f;
  if (n < 256) v = Wq[(size_t)k * 256 + n];
  else if (n < 260) v = Ww[(size_t)k * 4 + (n - 256)];
  P[idx] = f2bf(v);
}

__global__ __launch_bounds__(256) void pack_k(const float* __restrict__ Wk,
                                              short* __restrict__ P) {
  int idx = blockIdx.x * 256 + threadIdx.x;  // total 4*32*2*64*8
  int j = idx & 7;
  int lane = (idx >> 3) & 63;
  int ks = (idx >> 9) & 1;
  int k64 = (idx >> 10) & 31;
  int jt = idx >> 15;
  int n = jt * 16 + (lane & 15);
  int k = k64 * 64 + ks * 32 + (lane >> 4) * 8 + j;
  P[idx] = f2bf(Wk[(size_t)k * 64 + n]);
}

// proj v8 = r3's 4-deep ring + r6's packed B. History: r6 removed the
// line-request bottleneck (B was 64 lines/inst) but period stayed ~5000 cyc:
// the 2-deep pipeline gives a stage only ONE period (~1.2k cyc) of
// issue-to-use distance vs ~2-3k cyc HBM latency under load. Depth condition
// (D-1)*P >= L needs D>=4. r3 tested D=4 while STILL line-bound -> null;
// post-r6 the depth can pay. Correctness chain unchanged from r3: B(t) is
// issued before stage(t+2)/(t+3), so the compiler's wait-for-B(t) before
// MFMA(t) force-drains only stage(t+1) (needed next iter); stages t+2,t+3
// stay in flight (~2 periods of latency cover). Raw s_barrier never drains.
template <int NJ, bool QP>
__device__ __forceinline__ void proj_body(const float* __restrict__ X,
                                          const short* __restrict__ P,
                                          short* __restrict__ O,
                                          float* __restrict__ wI, int blk,
                                          float* As /* [4][2048] LDS */) {
  const int tid = threadIdx.x;
  const int wave = tid >> 6, lane = tid & 63;
  const int l15 = lane & 15, quad = lane >> 4;
  const int m0 = blk * 32;
  const int ldo = QP ? 256 : 64;
  constexpr int NB = NJ * 2;  // B register loads per iteration

  int jt[NJ];
#pragma unroll
  for (int jj = 0; jj < NJ; ++jj) jt[jj] = QP ? (jj < 4 ? jj * 4 + wave : 16 + wave) : wave;

  // Packed-B bases: per jt: 32 k64 * 2 ks * 64 lanes * 8 shorts = 32768.
  const short* wb[NJ];
#pragma unroll
  for (int jj = 0; jj < NJ; ++jj) wb[jj] = P + (size_t)jt[jj] * 32768 + lane * 8;

  // Stage: thread t fills linear LDS slots {t*16, 4096+t*16} (rows srow,
  // srow+16) from pre-swizzled global chunk (t&15)^srow (rule #21).
  const int srow = tid >> 4;
  const int schunk = (tid & 15) ^ srow;
  const float* s0 = X + (size_t)(m0 + srow) * DM + schunk * 4;
  const float* s1 = X + (size_t)(m0 + 16 + srow) * DM + schunk * 4;
  const int d0 = tid * 16, d1 = 4096 + tid * 16;
  char* lb = (char*)As;

  // Prologue: S(0),S(1),S(2), then B(0). Manual wait drains own S(0) share
  // (leaves S(1),S(2),B(0) = 4+NB in flight); barrier makes S(0) global.
#pragma unroll
  for (int s = 0; s < 3; ++s) {
    __builtin_amdgcn_global_load_lds((gvoid*)(s0 + s * 64), (lvoid*)(lb + s * 8192 + d0), 16, 0, 0);
    __builtin_amdgcn_global_load_lds((gvoid*)(s1 + s * 64), (lvoid*)(lb + s * 8192 + d1), 16, 0, 0);
  }
  bf16x8 bb[2][NJ][2];
#pragma unroll
  for (int jj = 0; jj < NJ; ++jj)
#pragma unroll
    for (int ks = 0; ks < 2; ++ks)
      bb[0][jj][ks] = *(const bf16x8*)(wb[jj] + ks * 512);
  __builtin_amdgcn_sched_barrier(0);
  asm volatile("s_waitcnt vmcnt(%0)" ::"i"(4 + NB));
  __builtin_amdgcn_sched_barrier(0);
  __builtin_amdgcn_s_barrier();

  const f32x4 z = {0.f, 0.f, 0.f, 0.f};
  f32x4 acc[NJ][2];
#pragma unroll
  for (int jj = 0; jj < NJ; ++jj)
#pragma unroll
    for (int i = 0; i < 2; ++i) acc[jj][i] = z;

  auto loadB = [&](int t1, int bbi) {
#pragma unroll
    for (int jj = 0; jj < NJ; ++jj)
#pragma unroll
      for (int ks = 0; ks < 2; ++ks)
        bb[bbi][jj][ks] = *(const bf16x8*)(wb[jj] + t1 * 1024 + ks * 512);
  };
  auto stage = [&](int t3) {
    char* l = lb + (t3 & 3) * 8192;
    __builtin_amdgcn_global_load_lds((gvoid*)(s0 + t3 * 64), (lvoid*)(l + d0), 16, 0, 0);
    __builtin_amdgcn_global_load_lds((gvoid*)(s1 + t3 * 64), (lvoid*)(l + d1), 16, 0, 0);
  };
  auto compute = [&](int cur, int bbi) {
    const float* Ab = As + cur * 2048;
    bf16x8 abf[2][2];
#pragma unroll
    for (int i = 0; i < 2; ++i)
#pragma unroll
      for (int ks = 0; ks < 2; ++ks) {
        const int rb = (i * 16 + l15) * 64;
        const int cg = ks * 8 + quad * 2;
        f32x4 a0 = *(const f32x4*)(Ab + rb + ((cg ^ l15) << 2));
        f32x4 a1 = *(const f32x4*)(Ab + rb + (((cg + 1) ^ l15) << 2));
        abf[i][ks] = cvt8(a0, a1);
      }
#pragma unroll
    for (int jj = 0; jj < NJ; ++jj)
#pragma unroll
      for (int i = 0; i < 2; ++i)
#pragma unroll
        for (int ks = 0; ks < 2; ++ks)
          acc[jj][i] = __builtin_amdgcn_mfma_f32_16x16x32_bf16(abf[i][ks], bb[bbi][jj][ks],
                                                               acc[jj][i], 0, 0, 0);
  };

#pragma unroll 4
  for (int t = 0; t < 28; ++t) {
    loadB(t + 1, (t + 1) & 1);           // B first: its (auto) wait never drains S(t+2,3)
    __builtin_amdgcn_sched_barrier(0);
    stage(t + 3);                        // 3 stages in flight, never drained
    __builtin_amdgcn_sched_barrier(0);
    compute(t & 3, t & 1);
    __builtin_amdgcn_sched_barrier(0);
    __builtin_amdgcn_s_barrier();        // raw: no waitcnt drain
  }
  // Peeled tail, static ring/parity indices (rule #20).
  loadB(29, 1);
  __builtin_amdgcn_sched_barrier(0);
  stage(31);
  __builtin_amdgcn_sched_barrier(0);
  compute(0, 0);  // t=28
  __builtin_amdgcn_sched_barrier(0);
  __builtin_amdgcn_s_barrier();

  loadB(30, 0);
  __builtin_amdgcn_sched_barrier(0);
  compute(1, 1);  // t=29
  __builtin_amdgcn_sched_barrier(0);
  __builtin_amdgcn_s_barrier();

  loadB(31, 1);
  __builtin_amdgcn_sched_barrier(0);
  compute(2, 0);  // t=30
  __builtin_amdgcn_sched_barrier(0);
  __builtin_amdgcn_s_barrier();

  compute(3, 1);  // t=31

  // C/D: row = quad*4 + r, col = l15
#pragma unroll
  for (int jj = 0; jj < NJ; ++jj) {
    if (QP && jt[jj] >= 16) {
      if (jt[jj] == 16 && l15 < 4) {  // Ww columns -> wI (f32)
#pragma unroll
        for (int i = 0; i < 2; ++i)
#pragma unroll
          for (int r = 0; r < 4; ++r)
            wI[(size_t)(m0 + i * 16 + quad * 4 + r) * NH + l15] = acc[jj][i][r];
      }
    } else {
#pragma unroll
      for (int i = 0; i < 2; ++i)
#pragma unroll
        for (int r = 0; r < 4; ++r)
          O[(size_t)(m0 + i * 16 + quad * 4 + r) * ldo + jt[jj] * 16 + l15] =
              f2bf(acc[jj][i][r]);
    }
  }
}

__global__ __launch_bounds__(256, 2) void proj_fused(const float* __restrict__ xq,
                                                     const float* __restrict__ xk,
                                                     const short* __restrict__ Pq,
                                                     const short* __restrict__ Pk,
                                                     short* __restrict__ qb,
                                                     short* __restrict__ kb,
                                                     float* __restrict__ wIb) {
  __shared__ __align__(16) float As[4][2048];  // 32 KB: 4-deep ring of [32r][64 f32]
  if (blockIdx.x < 256)
    proj_body<5, true>(xq, Pq, qb, wIb, blockIdx.x, &As[0][0]);
  else
    proj_body<1, false>(xk, Pk, kb, nullptr, blockIdx.x - 256, &As[0][0]);
}

// out[b][q][k] = sum_h wI[b,q,h] * relu(qb[b,q,h,:] . kb[b,k,:])
// 128x128 tile/block, 4 waves of 64x64. No LDS/barriers; af double-buffered over heads.
__global__ __launch_bounds__(256, 2) void score_kernel(const short* __restrict__ qb,
                                                       const short* __restrict__ kb,
                                                       const float* __restrict__ wI,
                                                       float* __restrict__ out) {
  const int b = blockIdx.z;
  const int qt = blockIdx.y;
  const int kt = blockIdx.x;
  const int tid = threadIdx.x;
  const int wave = tid >> 6, lane = tid & 63;
  const int wm = wave >> 1, wn = wave & 1;
  const int l15 = lane & 15, quad = lane >> 4;

  // Key fragments: B[k=quad*8+j][n=l15]; reused across all heads.
  bf16x8 bf[4][2];
  {
    const short* kbase =
        kb + (size_t)(b * TKS + kt * 128 + wn * 64 + l15) * DI + quad * 8;
#pragma unroll
    for (int j = 0; j < 4; ++j)
#pragma unroll
      for (int ks = 0; ks < 2; ++ks)
        bf[j][ks] = *(const bf16x8*)(kbase + j * 16 * DI + ks * 32);
  }

  const f32x4 z = {0.f, 0.f, 0.f, 0.f};
  f32x4 facc[4][4];
#pragma unroll
  for (int i = 0; i < 4; ++i)
#pragma unroll
    for (int j = 0; j < 4; ++j) facc[i][j] = z;

  const short* qbase =
      qb + (size_t)(b * TQS + qt * 128 + wm * 64 + l15) * (NH * DI) + quad * 8;
  const float* wbase = wI + (size_t)(b * TQS + qt * 128 + wm * 64 + quad * 4) * NH;

  bf16x8 af[2][4][2];
#pragma unroll
  for (int i = 0; i < 4; ++i)
#pragma unroll
    for (int ks = 0; ks < 2; ++ks)
      af[0][i][ks] = *(const bf16x8*)(qbase + i * 16 * (NH * DI) + ks * 32);

#pragma unroll
  for (int h = 0; h < NH; ++h) {
    if (h < NH - 1) {  // prefetch next head's A fragments (covered by MFMA+epilogue)
#pragma unroll
      for (int i = 0; i < 4; ++i)
#pragma unroll
        for (int ks = 0; ks < 2; ++ks)
          af[(h + 1) & 1][i][ks] =
              *(const bf16x8*)(qbase + (h + 1) * DI + i * 16 * (NH * DI) + ks * 32);
    }

    f32x4 acc[4][4];
#pragma unroll
    for (int i = 0; i < 4; ++i)
#pragma unroll
      for (int j = 0; j < 4; ++j) acc[i][j] = z;

#pragma unroll
    for (int ks = 0; ks < 2; ++ks)
#pragma unroll
      for (int i = 0; i < 4; ++i)
#pragma unroll
        for (int j = 0; j < 4; ++j)
          acc[i][j] = __builtin_amdgcn_mfma_f32_16x16x32_bf16(
              af[h & 1][i][ks], bf[j][ks], acc[i][j], 0, 0, 0);

#pragma unroll
    for (int i = 0; i < 4; ++i) {
      float wv[4];
#pragma unroll
      for (int r = 0; r < 4; ++r) wv[r] = wbase[(i * 16 + r) * NH + h];
#pragma unroll
      for (int j = 0; j < 4; ++j)
#pragma unroll
        for (int r = 0; r < 4; ++r)
          facc[i][j][r] += wv[r] * fmaxf(acc[i][j][r], 0.f);
    }
  }

  float* obase = out + (size_t)b * TQS * TKS +
                 (size_t)(qt * 128 + wm * 64 + quad * 4) * TKS + kt * 128 + wn * 64 + l15;
#pragma unroll
  for (int i = 0; i < 4; ++i)
#pragma unroll
    for (int r = 0; r < 4; ++r)
#pragma unroll
      for (int j = 0; j < 4; ++j)
        __builtin_nontemporal_store(facc[i][j][r],
                                    &obase[(size_t)(i * 16 + r) * TKS + j * 16]);
}

extern "C" void kernel_launch(void* const* d_in, const int* in_sizes, int n_in,
                              void* d_out, int out_size, void* d_ws, size_t ws_size,
                              hipStream_t stream) {
  const float* x_q = (const float*)d_in[0];  // [2,4096,2048]
  const float* x_k = (const float*)d_in[1];  // [2,4096,2048]
  const float* Wq  = (const float*)d_in[2];  // [2048,256]
  const float* Ww  = (const float*)d_in[3];  // [2048,4]
  const float* Wk  = (const float*)d_in[4];  // [2048,64]
  float* out = (float*)d_out;                // [2,4096,4096]

  char* ws = (char*)d_ws;
  short* qbuf = (short*)(ws);                              // 8192*256 bf16 = 4 MB
  short* kbuf = (short*)(ws + (4u << 20));                 // 8192*64  bf16 = 1 MB
  float* wIb  = (float*)(ws + (5u << 20));                 // 8192*4 f32 = 128 KB
  short* Pq   = (short*)(ws + (5u << 20) + (128u << 10));  // 20*32768 bf16 = 1.25 MB
  short* Pk   = (short*)(ws + (7u << 20));                 // 4*32768 bf16 = 256 KB

  pack_qw<<<(20 * 32768) / 256, 256, 0, stream>>>(Wq, Ww, Pq);
  pack_k<<<(4 * 32768) / 256, 256, 0, stream>>>(Wk, Pk);

  // Fused projections: blocks 0-255 -> q (+w), 256-511 -> k. x read exactly once.
  proj_fused<<<512, 256, 0, stream>>>(x_q, x_k, Pq, Pk, qbuf, kbuf, wIb);

  score_kernel<<<dim3(TKS / 128, TQS / 128, BB), 256, 0, stream>>>(qbuf, kbuf, wIb, out);
}